// Round 6
// baseline (97.291 us; speedup 1.0000x reference)
//
#include <hip/hip_runtime.h>
#include <cmath>

#define HH 32
#define WW 32
#define HWN 1024
#define NCH 384
#define NHH 12
#define DHH 32
#define NGG 6

typedef __attribute__((ext_vector_type(8))) short short8;
typedef __attribute__((ext_vector_type(4))) float f32x4;

static constexpr float SCALE_QK = 0.17677669529663689f;     // 32^-0.5
static constexpr float INV_SCALE_QK = 5.656854249492381f;   // 32^0.5

__device__ inline unsigned short f2bf(float f) {
    union { float f; unsigned u; } v; v.f = f;
    return (unsigned short)((v.u + 0x7FFFu + ((v.u >> 16) & 1u)) >> 16);  // RNE
}

// ---------------------------------------------------------------------------
// K0 prep: (a) zero-padded head-major RPE table rpad[12][67][68];
//          (b) bf16 transposed conv weights Wg[n=384][k=576];
//          (c) bf16 transposed proj weights Wt[4][n=384][k=384] (q,k,v,o);
//          (d) bf16 copy of x -> xb[2048*384].
// ---------------------------------------------------------------------------
#define RPAD_N (12 * 67 * 68)
#define WG_N   (384 * 576)
#define WT_N   (4 * 384 * 384)
#define XB_N   (2048 * 384)
#define OFF1 RPAD_N
#define OFF2 (OFF1 + WG_N)
#define OFF3 (OFF2 + WT_N)
#define PREP_TOT (OFF3 + XB_N)
__global__ __launch_bounds__(256) void prep_kernel(
    const float* __restrict__ rpe, const float* __restrict__ w_off,
    const float* __restrict__ wq, const float* __restrict__ wk,
    const float* __restrict__ wv, const float* __restrict__ wo,
    const float* __restrict__ x,
    float* __restrict__ rpad, unsigned short* __restrict__ Wg,
    unsigned short* __restrict__ Wt, unsigned short* __restrict__ xb)
{
    int idx = blockIdx.x * 256 + threadIdx.x;
    if (idx < OFF1) {
        int h = idx / (67 * 68);
        int rem = idx - h * (67 * 68);
        int row = rem / 68, col = rem - row * 68;
        int r = row - 2, c = col - 2;
        float v = 0.f;
        if (r >= 0 && r < 63 && c >= 0 && c < 63)
            v = rpe[(r * 63 + c) * NHH + h];
        rpad[idx] = v;
    } else if (idx < OFF2) {
        int w = idx - OFF1;
        int n = w / 576, k = w - n * 576;
        Wg[n * 576 + k] = f2bf(w_off[k * NCH + n]);
    } else if (idx < OFF3) {
        int w = idx - OFF2;
        int z = w / (NCH * NCH);
        int rem = w - z * (NCH * NCH);
        int n = rem / NCH, k = rem - n * NCH;
        const float* Wz = (z == 0) ? wq : (z == 1) ? wk : (z == 2) ? wv : wo;
        Wt[w] = f2bf(Wz[k * NCH + n]);
    } else if (idx < PREP_TOT) {
        int e = idx - OFF3;
        xb[e] = f2bf(x[e]);
    }
}

// ---------------------------------------------------------------------------
// MFMA GEMM, pure bf16 operands (A[m][k], Wt[n][k]), fp32 accum.
// kmode=1: z selects -> Qg bf16 group-major (*SCALE_QK) / Kb [bh][q][d] /
// Vt [bh][d][k]. kmode=0: fp32 C + bias.
// ---------------------------------------------------------------------------
__global__ __launch_bounds__(256) void gemm_mfma(
    const unsigned short* __restrict__ Abf, const unsigned short* __restrict__ Wt,
    const float* __restrict__ b0, const float* __restrict__ b1, const float* __restrict__ b2,
    float* __restrict__ Cf,
    unsigned short* __restrict__ Qg, unsigned short* __restrict__ Kb,
    unsigned short* __restrict__ Vt, int kmode)
{
    const int z = blockIdx.z;
    const unsigned short* Wm = Wt + z * (NCH * NCH);
    const float* bm = (z == 0) ? b0 : (z == 1) ? b1 : b2;
    const int lane = threadIdx.x & 63;
    const int wid  = threadIdx.x >> 6;
    const int g    = lane >> 4;
    const int l15  = lane & 15;
    const int m0w  = blockIdx.x * 64 + (wid >> 1) * 32;
    const int n0w  = blockIdx.y * 64 + (wid & 1) * 32;

    f32x4 acc[2][2] = {};

#pragma unroll 4
    for (int k0 = 0; k0 < NCH; k0 += 32) {
        short8 af[2], bfr[2];
#pragma unroll
        for (int i = 0; i < 2; ++i)
            af[i] = *(const short8*)(Abf + (m0w + i * 16 + l15) * NCH + k0 + g * 8);
#pragma unroll
        for (int j = 0; j < 2; ++j)
            bfr[j] = *(const short8*)(Wm + (n0w + j * 16 + l15) * NCH + k0 + g * 8);
#pragma unroll
        for (int i = 0; i < 2; ++i)
#pragma unroll
            for (int j = 0; j < 2; ++j)
                acc[i][j] = __builtin_amdgcn_mfma_f32_16x16x32_bf16(
                    af[i], bfr[j], acc[i][j], 0, 0, 0);
    }

    if (kmode == 0) {
#pragma unroll
        for (int i = 0; i < 2; ++i)
#pragma unroll
            for (int j = 0; j < 2; ++j) {
                int col = n0w + j * 16 + l15;
                float bias = bm[col];
#pragma unroll
                for (int r = 0; r < 4; ++r) {
                    int row = m0w + i * 16 + g * 4 + r;
                    Cf[row * NCH + col] = acc[i][j][r] + bias;
                }
            }
    } else if (z == 2) {
#pragma unroll
        for (int i = 0; i < 2; ++i) {
            int krow = m0w + i * 16 + g * 4;
            int b_ = krow >> 10, kk = krow & 1023;
#pragma unroll
            for (int j = 0; j < 2; ++j) {
                int col = n0w + j * 16 + l15;
                int h = col >> 5, d = col & 31;
                float bias = bm[col];
                unsigned short s0 = f2bf(acc[i][j][0] + bias);
                unsigned short s1 = f2bf(acc[i][j][1] + bias);
                unsigned short s2 = f2bf(acc[i][j][2] + bias);
                unsigned short s3 = f2bf(acc[i][j][3] + bias);
                uint2 pk;
                pk.x = (unsigned)s0 | ((unsigned)s1 << 16);
                pk.y = (unsigned)s2 | ((unsigned)s3 << 16);
                *(uint2*)&Vt[(((b_ * NHH) + h) * DHH + d) * HWN + kk] = pk;
            }
        }
    } else if (z == 0) {
        // Qg group-major: [b][g6][p][c64], c = (h&1)*32 + d, scaled
#pragma unroll
        for (int i = 0; i < 2; ++i)
#pragma unroll
            for (int j = 0; j < 2; ++j) {
                int col = n0w + j * 16 + l15;
                int h = col >> 5, d = col & 31;
                float bias = bm[col];
#pragma unroll
                for (int r = 0; r < 4; ++r) {
                    int row = m0w + i * 16 + g * 4 + r;
                    int b_ = row >> 10, q = row & 1023;
                    Qg[(((b_ * NGG + (h >> 1)) * HWN + q) * 64) + (h & 1) * 32 + d] =
                        f2bf((acc[i][j][r] + bias) * SCALE_QK);
                }
            }
    } else {
#pragma unroll
        for (int i = 0; i < 2; ++i)
#pragma unroll
            for (int j = 0; j < 2; ++j) {
                int col = n0w + j * 16 + l15;
                int h = col >> 5, d = col & 31;
                float bias = bm[col];
#pragma unroll
                for (int r = 0; r < 4; ++r) {
                    int row = m0w + i * 16 + g * 4 + r;
                    int b_ = row >> 10, q = row & 1023;
                    Kb[(((b_ * NHH) + h) * HWN + q) * DHH + d] = f2bf(acc[i][j][r] + bias);
                }
            }
    }
}

// ---------------------------------------------------------------------------
// K2a: grouped 3x3 conv as shifted-window MFMA GEMM.
// Block = 4 waves (wave = one N16 slice), tile M32 x N64 per block.
// ---------------------------------------------------------------------------
__global__ __launch_bounds__(256) void conv_mfma(
    const unsigned short* __restrict__ Qg, const unsigned short* __restrict__ Wg,
    const float* __restrict__ b_off, float* __restrict__ conv_out)
{
    const int bg = blockIdx.y;            // 0..11 = b*6+g
    const int b = bg / NGG, g = bg - b * NGG;
    const int m0 = blockIdx.x * 32;       // image row tile
    const int tid = threadIdx.x;
    const int wid = tid >> 6;             // N16 slice 0..3
    const int lane = tid & 63;
    const int l15 = lane & 15, gk = lane >> 4;

    const unsigned short* Ab = Qg + (bg * HWN) * 64;
    const unsigned short* Bb = Wg + (g * 64 + wid * 16) * 576;

    f32x4 acc[2] = {};
    const int pr0 = m0 + l15, pr1 = m0 + 16 + l15;
    const int irow = m0 >> 5;
    const int4 zz = {0, 0, 0, 0};

#pragma unroll
    for (int kh = 0; kh < 3; ++kh) {
        int ii = irow + kh - 1;
        if ((unsigned)ii >= (unsigned)HH) continue;   // uniform skip (zero rows)
#pragma unroll
        for (int kw = 0; kw < 3; ++kw) {
            int dp = (kh - 1) * 32 + (kw - 1);
            bool v0 = (unsigned)(l15 + kw - 1) < (unsigned)WW;
            bool v1 = (unsigned)(16 + l15 + kw - 1) < (unsigned)WW;
            int p0 = min(max(pr0 + dp, 0), HWN - 1);
            int p1 = min(max(pr1 + dp, 0), HWN - 1);
            const int kt = (kh * 3 + kw) * 64;
#pragma unroll
            for (int cc = 0; cc < 2; ++cc) {
                int4 ra = *(const int4*)(Ab + p0 * 64 + cc * 32 + gk * 8);
                int4 rb = *(const int4*)(Ab + p1 * 64 + cc * 32 + gk * 8);
                int4 a0i = v0 ? ra : zz;
                int4 a1i = v1 ? rb : zz;
                short8 a0 = *(short8*)&a0i;
                short8 a1 = *(short8*)&a1i;
                short8 bf = *(const short8*)(Bb + l15 * 576 + kt + cc * 32 + gk * 8);
                acc[0] = __builtin_amdgcn_mfma_f32_16x16x32_bf16(a0, bf, acc[0], 0, 0, 0);
                acc[1] = __builtin_amdgcn_mfma_f32_16x16x32_bf16(a1, bf, acc[1], 0, 0, 0);
            }
        }
    }

    const int ch = g * 64 + wid * 16 + l15;
    const float bias = b_off[ch];
#pragma unroll
    for (int mi = 0; mi < 2; ++mi)
#pragma unroll
        for (int r = 0; r < 4; ++r) {
            int prow = m0 + mi * 16 + gk * 4 + r;
            conv_out[((b * HWN) + prow) * NCH + ch] = acc[mi][r] * INV_SCALE_QK + bias;
        }
}

// ---------------------------------------------------------------------------
// K2b: per-pixel LN -> GELU -> per-group offset proj -> pos/ref + per-key
// bilinear precompute. 1 pixel per block, thread = channel, wave = group.
// ---------------------------------------------------------------------------
__global__ __launch_bounds__(384) void ln_offset_kernel(
    const float* __restrict__ co, const float* __restrict__ ln_g,
    const float* __restrict__ ln_b, const float* __restrict__ w_offp,
    float* __restrict__ pos_out, float* __restrict__ ref_out,
    float4* __restrict__ kw4, int* __restrict__ kbase)
{
    const int pg = blockIdx.x;            // 0..2047
    const int b = pg >> 10, p = pg & 1023;
    const int i = p >> 5, j = p & 31;
    const int tid = threadIdx.x;
    const int g = tid >> 6, lane = tid & 63;

    __shared__ float red[6][2];

    float v = co[pg * NCH + tid];
    float s1 = v, s2 = v * v;
#pragma unroll
    for (int off = 32; off > 0; off >>= 1) {
        s1 += __shfl_xor(s1, off);
        s2 += __shfl_xor(s2, off);
    }
    if (lane == 0) { red[g][0] = s1; red[g][1] = s2; }
    __syncthreads();
    float t1s = 0.f, t2s = 0.f;
#pragma unroll
    for (int w = 0; w < 6; ++w) { t1s += red[w][0]; t2s += red[w][1]; }
    float mu  = t1s * (1.f / 384.f);
    float var = t2s * (1.f / 384.f) - mu * mu;
    float rs2 = rsqrtf(var + 1e-3f);
    float on = (v - mu) * rs2 * ln_g[tid] + ln_b[tid];
    float t = 0.7978845608028654f * (on + 0.044715f * on * on * on);
    float ge = on * 0.5f * (1.f + tanhf(t));

    float t0 = ge * w_offp[lane * 2 + 0];
    float t1 = ge * w_offp[lane * 2 + 1];
#pragma unroll
    for (int off = 32; off > 0; off >>= 1) {
        t0 += __shfl_xor(t0, off);
        t1 += __shfl_xor(t1, off);
    }
    if (lane == 0) {
        float o0 = tanhf(t0) * 16.f + (float)j;   // pos.x
        float o1 = tanhf(t1) * 16.f + (float)i;   // pos.y
        int kidx = (b * NGG + g) * HWN + p;
        pos_out[kidx * 2]     = o0; pos_out[kidx * 2 + 1] = o1;
        ref_out[kidx * 2]     = (float)j; ref_out[kidx * 2 + 1] = (float)i;
        float mp1 = -o1, mp0 = -o0;
        float fx = floorf(mp1), fy = floorf(mp0);
        float wx = mp1 - fx, wy = mp0 - fy;
        float4 w4;
        w4.x = (1.f - wx) * (1.f - wy);
        w4.y = wx * (1.f - wy);
        w4.z = (1.f - wx) * wy;
        w4.w = wx * wy;
        kw4[kidx] = w4;
        kbase[kidx] = ((int)fx & 0xFFFF) | ((int)fy << 16);
    }
}

// ---------------------------------------------------------------------------
// K3: MFMA flash attention, 4-way key-split. kw4/kbase read direct from L2
// (no LDS staging: each block's waves consume them exactly once).
// LDS ~32.6 KB -> 4 blocks/CU.
// ---------------------------------------------------------------------------
__global__ __launch_bounds__(256) void attn_mfma(
    const unsigned short* __restrict__ Qg, const unsigned short* __restrict__ Kb,
    const unsigned short* __restrict__ Vt, const float4* __restrict__ kw4,
    const int* __restrict__ kbase, const float* __restrict__ rpad,
    unsigned short* __restrict__ o_bf)
{
    const int bh = blockIdx.y;
    const int b = bh / NHH;
    const int h = bh - b * NHH;
    const int tid = threadIdx.x;
    const int wid = tid >> 6;
    const int lane = tid & 63;
    const int g = lane >> 4;
    const int l15 = lane & 15;
    const int q = blockIdx.x * 16 + l15;

    __shared__ float rsT[67 * 68];
    __shared__ unsigned short P_lds[4][16][40];
    __shared__ float obuf[4][16][34];
    __shared__ float mlbuf[4][2][16];

    {
        const float4* rp = (const float4*)(rpad + h * (67 * 68));
        float4* rd = (float4*)rsT;
        for (int idx = tid; idx < (67 * 68) / 4; idx += 256) rd[idx] = rp[idx];
    }

    short8 qf = *(const short8*)(Qg + ((b * NGG + (h >> 1)) * HWN + q) * 64 + (h & 1) * 32 + g * 8);
    const int qi = q >> 5;
    const int qj = q & 31;

    const unsigned short* kbg = Kb + (bh * HWN) * DHH;
    const unsigned short* vbase = Vt + (bh * DHH) * HWN;
    const float4* kwg = kw4 + (b * NGG + (h >> 1)) * HWN;
    const int* kbg2 = kbase + (b * NGG + (h >> 1)) * HWN;

    f32x4 oacc[2] = {};
    float m = -1e30f, lp = 0.f;
    const f32x4 z4 = {0.f, 0.f, 0.f, 0.f};

    __syncthreads();

#pragma unroll 1
    for (int c = 0; c < 8; ++c) {
        const int kc0 = wid * 256 + c * 32;
        f32x4 st[2];
#pragma unroll
        for (int t = 0; t < 2; ++t) {
            short8 kf = *(const short8*)(kbg + (kc0 + t * 16 + l15) * DHH + g * 8);
            st[t] = __builtin_amdgcn_mfma_f32_16x16x32_bf16(kf, qf, z4, 0, 0, 0);
        }
#pragma unroll
        for (int t = 0; t < 2; ++t) {
#pragma unroll
            for (int r = 0; r < 4; ++r) {
                int k = kc0 + t * 16 + g * 4 + r;
                float4 w4 = kwg[k];
                int bp = kbg2[k];
                int ix = qi + ((bp << 16) >> 16);
                int iy = qj + (bp >> 16);
                int cx = min(max(ix, -2), 63) + 2;
                int cy = min(max(iy, -2), 63) + 2;
                int a = cy * 68 + cx;
                st[t][r] += w4.x * rsT[a] + w4.y * rsT[a + 1]
                          + w4.z * rsT[a + 68] + w4.w * rsT[a + 69];
            }
        }
        float cm = fmaxf(fmaxf(fmaxf(st[0][0], st[0][1]), fmaxf(st[0][2], st[0][3])),
                         fmaxf(fmaxf(st[1][0], st[1][1]), fmaxf(st[1][2], st[1][3])));
        cm = fmaxf(cm, __shfl_xor(cm, 16));
        cm = fmaxf(cm, __shfl_xor(cm, 32));
        if (cm > m + 8.f) {
            float scl = __expf(m - cm);
            m = cm;
            lp *= scl;
            oacc[0] *= scl;
            oacc[1] *= scl;
        }
#pragma unroll
        for (int t = 0; t < 2; ++t) {
            float p0 = __expf(st[t][0] - m);
            float p1 = __expf(st[t][1] - m);
            float p2 = __expf(st[t][2] - m);
            float p3 = __expf(st[t][3] - m);
            lp += (p0 + p1) + (p2 + p3);
            uint2 pk;
            pk.x = (unsigned)f2bf(p0) | ((unsigned)f2bf(p1) << 16);
            pk.y = (unsigned)f2bf(p2) | ((unsigned)f2bf(p3) << 16);
            *(uint2*)&P_lds[wid][l15][t * 16 + g * 4] = pk;
        }
        short8 pf = *(const short8*)&P_lds[wid][l15][g * 8];
#pragma unroll
        for (int dt = 0; dt < 2; ++dt) {
            short8 vf = *(const short8*)(vbase + (dt * 16 + l15) * HWN + kc0 + g * 8);
            oacc[dt] = __builtin_amdgcn_mfma_f32_16x16x32_bf16(vf, pf, oacc[dt], 0, 0, 0);
        }
    }

    lp += __shfl_xor(lp, 16);
    lp += __shfl_xor(lp, 32);
    if (g == 0) {
        mlbuf[wid][0][l15] = m;
        mlbuf[wid][1][l15] = lp;
    }
#pragma unroll
    for (int dt = 0; dt < 2; ++dt)
#pragma unroll
        for (int r = 0; r < 4; ++r)
            obuf[wid][l15][dt * 16 + g * 4 + r] = oacc[dt][r];
    __syncthreads();

    const int q16 = tid >> 4;
    const int dp = (tid & 15) * 2;
    float m0 = mlbuf[0][0][q16], m1 = mlbuf[1][0][q16];
    float m2 = mlbuf[2][0][q16], m3 = mlbuf[3][0][q16];
    float mstar = fmaxf(fmaxf(m0, m1), fmaxf(m2, m3));
    float w0 = __expf(m0 - mstar), w1 = __expf(m1 - mstar);
    float w2 = __expf(m2 - mstar), w3 = __expf(m3 - mstar);
    float lsum = w0 * mlbuf[0][1][q16] + w1 * mlbuf[1][1][q16]
               + w2 * mlbuf[2][1][q16] + w3 * mlbuf[3][1][q16];
    float inv = 1.f / lsum;
    unsigned out2 = 0;
#pragma unroll
    for (int u = 0; u < 2; ++u) {
        int d = dp + u;
        float o = w0 * obuf[0][q16][d] + w1 * obuf[1][q16][d]
                + w2 * obuf[2][q16][d] + w3 * obuf[3][q16][d];
        unsigned short s = f2bf(o * inv);
        out2 |= ((unsigned)s) << (u * 16);
    }
    int qn2 = blockIdx.x * 16 + q16;
    *(unsigned*)&o_bf[((b * HWN) + qn2) * NCH + h * DHH + dp] = out2;
}

// ---------------------------------------------------------------------------
extern "C" void kernel_launch(void* const* d_in, const int* in_sizes, int n_in,
                              void* d_out, int out_size, void* d_ws, size_t ws_size,
                              hipStream_t stream) {
    (void)in_sizes; (void)n_in; (void)out_size; (void)ws_size;
    const float* x      = (const float*)d_in[0];
    const float* w_off  = (const float*)d_in[1];
    const float* b_off  = (const float*)d_in[2];
    const float* ln_g   = (const float*)d_in[3];
    const float* ln_b   = (const float*)d_in[4];
    const float* w_offp = (const float*)d_in[5];
    const float* wq     = (const float*)d_in[6];
    const float* bq     = (const float*)d_in[7];
    const float* wk     = (const float*)d_in[8];
    const float* bk     = (const float*)d_in[9];
    const float* wv     = (const float*)d_in[10];
    const float* bv     = (const float*)d_in[11];
    const float* wo     = (const float*)d_in[12];
    const float* bo     = (const float*)d_in[13];
    const float* rpe    = (const float*)d_in[14];

    float* out     = (float*)d_out;
    float* y_out   = out;             // 786432
    float* pos_out = out + 786432;    // 24576
    float* ref_out = out + 811008;    // 24576

    float* ws = (float*)d_ws;
    unsigned short* Qg   = (unsigned short*)(ws);            // 786432 bf16
    unsigned short* Kb   = (unsigned short*)(ws + 393216);   // 786432 bf16
    unsigned short* Vt   = (unsigned short*)(ws + 786432);   // 786432 bf16
    unsigned short* o_bf = (unsigned short*)(ws + 1179648);  // 786432 bf16
    float*  rpad  = ws + 1376256;                            // 54672 f32
    float4* kw4   = (float4*)(ws + 1430928);                 // 12288 float4
    int*    kbase = (int*)(ws + 1480080);                    // 12288 int
    unsigned short* Wg = (unsigned short*)(ws + 1492368);    // 221184 bf16
    float* conv_ws = ws + 1602960;                           // 786432 f32
    unsigned short* Wt = (unsigned short*)(ws + 2389392);    // 589824 bf16
    unsigned short* xb = (unsigned short*)(ws + 2684304);    // 786432 bf16
    // total ~3077520 floats ~ 12.3 MB

    // K0: padded RPE + transposed bf16 conv/proj weights + bf16 x
    prep_kernel<<<dim3((PREP_TOT + 255) / 256), 256, 0, stream>>>(
        rpe, w_off, wq, wk, wv, wo, x, rpad, Wg, Wt, xb);

    // K1: q/k/v projections -> Qg (group-major, scaled), Kb, Vt
    gemm_mfma<<<dim3(32, 6, 3), 256, 0, stream>>>(
        xb, Wt, bq, bk, bv, nullptr, Qg, Kb, Vt, 1);

    // K2a: grouped conv via shifted-window MFMA (4 waves/block)
    conv_mfma<<<dim3(32, 12), 256, 0, stream>>>(Qg, Wg, b_off, conv_ws);

    // K2b: LN + GELU + offset proj -> pos/ref + per-key precompute
    ln_offset_kernel<<<dim3(2048), 384, 0, stream>>>(
        conv_ws, ln_g, ln_b, w_offp, pos_out, ref_out, kw4, kbase);

    // K3: MFMA flash attention
    attn_mfma<<<dim3(64, 24), 256, 0, stream>>>(
        Qg, Kb, Vt, kw4, kbase, rpad, o_bf);

    // K4: output projection -> y
    gemm_mfma<<<dim3(32, 6, 1), 256, 0, stream>>>(
        o_bf, Wt + 3 * NCH * NCH, bo, bo, bo, y_out, nullptr, nullptr, nullptr, 0);
}

// Round 8
// 92.528 us; speedup vs baseline: 1.0515x; 1.0515x over previous
//
#include <hip/hip_runtime.h>
#include <cmath>

#define HH 32
#define WW 32
#define HWN 1024
#define NCH 384
#define NHH 12
#define DHH 32
#define NGG 6

typedef __attribute__((ext_vector_type(8))) short short8;
typedef __attribute__((ext_vector_type(4))) float f32x4;

static constexpr float SCALE_QK = 0.17677669529663689f;     // 32^-0.5
static constexpr float INV_SCALE_QK = 5.656854249492381f;   // 32^0.5

__device__ inline unsigned short f2bf(float f) {
    union { float f; unsigned u; } v; v.f = f;
    return (unsigned short)((v.u + 0x7FFFu + ((v.u >> 16) & 1u)) >> 16);  // RNE
}

// ---------------------------------------------------------------------------
// K0 prep: (a) zero-padded head-major RPE table rpad[12][67][68];
//          (b) bf16 transposed conv weights Wg[n=384][k=576];
//          (c) bf16 transposed proj weights Wt[4][384][384] (q,k,v,o);
//          (d) bf16 copy of x.
// ---------------------------------------------------------------------------
#define RPAD_N (12 * 67 * 68)
#define WG_N   (384 * 576)
#define WT_N   (4 * 384 * 384)
#define XB_N   (2048 * 384)
#define OFF1 RPAD_N
#define OFF2 (OFF1 + WG_N)
#define OFF3 (OFF2 + WT_N)
#define PREP_TOT (OFF3 + XB_N)
__global__ __launch_bounds__(256) void prep_kernel(
    const float* __restrict__ rpe, const float* __restrict__ w_off,
    const float* __restrict__ wq, const float* __restrict__ wk,
    const float* __restrict__ wv, const float* __restrict__ wo,
    const float* __restrict__ x,
    float* __restrict__ rpad, unsigned short* __restrict__ Wg,
    unsigned short* __restrict__ Wt, unsigned short* __restrict__ xb)
{
    int idx = blockIdx.x * 256 + threadIdx.x;
    if (idx < OFF1) {
        int h = idx / (67 * 68);
        int rem = idx - h * (67 * 68);
        int row = rem / 68, col = rem - row * 68;
        int r = row - 2, c = col - 2;
        float v = 0.f;
        if (r >= 0 && r < 63 && c >= 0 && c < 63)
            v = rpe[(r * 63 + c) * NHH + h];
        rpad[idx] = v;
    } else if (idx < OFF2) {
        int w = idx - OFF1;
        int n = w / 576, k = w - n * 576;
        Wg[n * 576 + k] = f2bf(w_off[k * NCH + n]);
    } else if (idx < OFF3) {
        int w = idx - OFF2;
        int z = w / (NCH * NCH);
        int rem = w - z * (NCH * NCH);
        int n = rem / NCH, k = rem - n * NCH;
        const float* Wz = (z == 0) ? wq : (z == 1) ? wk : (z == 2) ? wv : wo;
        Wt[w] = f2bf(Wz[k * NCH + n]);
    } else if (idx < PREP_TOT) {
        int e = idx - OFF3;
        xb[e] = f2bf(x[e]);
    }
}

// ---------------------------------------------------------------------------
// MFMA GEMM, pure bf16 operands (A[m][k], Wt[n][k]), fp32 accum.
// kmode=1: z selects -> Qg bf16 group-major (*SCALE_QK) / Kb [bh][q][d] /
// Vt [bh][d][k]. kmode=0: fp32 C + bias.   (proven in R5 kernel)
// ---------------------------------------------------------------------------
__global__ __launch_bounds__(256) void gemm_mfma(
    const unsigned short* __restrict__ Abf, const unsigned short* __restrict__ Wt,
    const float* __restrict__ b0, const float* __restrict__ b1, const float* __restrict__ b2,
    float* __restrict__ Cf,
    unsigned short* __restrict__ Qg, unsigned short* __restrict__ Kb,
    unsigned short* __restrict__ Vt, int kmode)
{
    const int z = blockIdx.z;
    const unsigned short* Wm = Wt + z * (NCH * NCH);
    const float* bm = (z == 0) ? b0 : (z == 1) ? b1 : b2;
    const int lane = threadIdx.x & 63;
    const int wid  = threadIdx.x >> 6;
    const int g    = lane >> 4;
    const int l15  = lane & 15;
    const int m0w  = blockIdx.x * 64 + (wid >> 1) * 32;
    const int n0w  = blockIdx.y * 64 + (wid & 1) * 32;

    f32x4 acc[2][2] = {};

#pragma unroll 4
    for (int k0 = 0; k0 < NCH; k0 += 32) {
        short8 af[2], bfr[2];
#pragma unroll
        for (int i = 0; i < 2; ++i)
            af[i] = *(const short8*)(Abf + (m0w + i * 16 + l15) * NCH + k0 + g * 8);
#pragma unroll
        for (int j = 0; j < 2; ++j)
            bfr[j] = *(const short8*)(Wm + (n0w + j * 16 + l15) * NCH + k0 + g * 8);
#pragma unroll
        for (int i = 0; i < 2; ++i)
#pragma unroll
            for (int j = 0; j < 2; ++j)
                acc[i][j] = __builtin_amdgcn_mfma_f32_16x16x32_bf16(
                    af[i], bfr[j], acc[i][j], 0, 0, 0);
    }

    if (kmode == 0) {
#pragma unroll
        for (int i = 0; i < 2; ++i)
#pragma unroll
            for (int j = 0; j < 2; ++j) {
                int col = n0w + j * 16 + l15;
                float bias = bm[col];
#pragma unroll
                for (int r = 0; r < 4; ++r) {
                    int row = m0w + i * 16 + g * 4 + r;
                    Cf[row * NCH + col] = acc[i][j][r] + bias;
                }
            }
    } else if (z == 2) {
#pragma unroll
        for (int i = 0; i < 2; ++i) {
            int krow = m0w + i * 16 + g * 4;
            int b_ = krow >> 10, kk = krow & 1023;
#pragma unroll
            for (int j = 0; j < 2; ++j) {
                int col = n0w + j * 16 + l15;
                int h = col >> 5, d = col & 31;
                float bias = bm[col];
                unsigned short s0 = f2bf(acc[i][j][0] + bias);
                unsigned short s1 = f2bf(acc[i][j][1] + bias);
                unsigned short s2 = f2bf(acc[i][j][2] + bias);
                unsigned short s3 = f2bf(acc[i][j][3] + bias);
                uint2 pk;
                pk.x = (unsigned)s0 | ((unsigned)s1 << 16);
                pk.y = (unsigned)s2 | ((unsigned)s3 << 16);
                *(uint2*)&Vt[(((b_ * NHH) + h) * DHH + d) * HWN + kk] = pk;
            }
        }
    } else if (z == 0) {
        // Qg group-major: [b][g6][p][c64], c = (h&1)*32 + d, scaled
#pragma unroll
        for (int i = 0; i < 2; ++i)
#pragma unroll
            for (int j = 0; j < 2; ++j) {
                int col = n0w + j * 16 + l15;
                int h = col >> 5, d = col & 31;
                float bias = bm[col];
#pragma unroll
                for (int r = 0; r < 4; ++r) {
                    int row = m0w + i * 16 + g * 4 + r;
                    int b_ = row >> 10, q = row & 1023;
                    Qg[(((b_ * NGG + (h >> 1)) * HWN + q) * 64) + (h & 1) * 32 + d] =
                        f2bf((acc[i][j][r] + bias) * SCALE_QK);
                }
            }
    } else {
#pragma unroll
        for (int i = 0; i < 2; ++i)
#pragma unroll
            for (int j = 0; j < 2; ++j) {
                int col = n0w + j * 16 + l15;
                int h = col >> 5, d = col & 31;
                float bias = bm[col];
#pragma unroll
                for (int r = 0; r < 4; ++r) {
                    int row = m0w + i * 16 + g * 4 + r;
                    int b_ = row >> 10, q = row & 1023;
                    Kb[(((b_ * NHH) + h) * HWN + q) * DHH + d] = f2bf(acc[i][j][r] + bias);
                }
            }
    }
}

// ---------------------------------------------------------------------------
// K2a: grouped 3x3 conv as shifted-window MFMA GEMM (4 waves/block, proven R5).
// ---------------------------------------------------------------------------
__global__ __launch_bounds__(256) void conv_mfma(
    const unsigned short* __restrict__ Qg, const unsigned short* __restrict__ Wg,
    const float* __restrict__ b_off, float* __restrict__ conv_out)
{
    const int bg = blockIdx.y;
    const int b = bg / NGG, g = bg - b * NGG;
    const int m0 = blockIdx.x * 32;
    const int tid = threadIdx.x;
    const int wid = tid >> 6;
    const int lane = tid & 63;
    const int l15 = lane & 15, gk = lane >> 4;

    const unsigned short* Ab = Qg + (bg * HWN) * 64;
    const unsigned short* Bb = Wg + (g * 64 + wid * 16) * 576;

    f32x4 acc[2] = {};
    const int pr0 = m0 + l15, pr1 = m0 + 16 + l15;
    const int irow = m0 >> 5;
    const int4 zz = {0, 0, 0, 0};

#pragma unroll
    for (int kh = 0; kh < 3; ++kh) {
        int ii = irow + kh - 1;
        if ((unsigned)ii >= (unsigned)HH) continue;
#pragma unroll
        for (int kw = 0; kw < 3; ++kw) {
            int dp = (kh - 1) * 32 + (kw - 1);
            bool v0 = (unsigned)(l15 + kw - 1) < (unsigned)WW;
            bool v1 = (unsigned)(16 + l15 + kw - 1) < (unsigned)WW;
            int p0 = min(max(pr0 + dp, 0), HWN - 1);
            int p1 = min(max(pr1 + dp, 0), HWN - 1);
            const int kt = (kh * 3 + kw) * 64;
#pragma unroll
            for (int cc = 0; cc < 2; ++cc) {
                int4 ra = *(const int4*)(Ab + p0 * 64 + cc * 32 + gk * 8);
                int4 rb = *(const int4*)(Ab + p1 * 64 + cc * 32 + gk * 8);
                int4 a0i = v0 ? ra : zz;
                int4 a1i = v1 ? rb : zz;
                short8 a0 = *(short8*)&a0i;
                short8 a1 = *(short8*)&a1i;
                short8 bf = *(const short8*)(Bb + l15 * 576 + kt + cc * 32 + gk * 8);
                acc[0] = __builtin_amdgcn_mfma_f32_16x16x32_bf16(a0, bf, acc[0], 0, 0, 0);
                acc[1] = __builtin_amdgcn_mfma_f32_16x16x32_bf16(a1, bf, acc[1], 0, 0, 0);
            }
        }
    }

    const int ch = g * 64 + wid * 16 + l15;
    const float bias = b_off[ch];
#pragma unroll
    for (int mi = 0; mi < 2; ++mi)
#pragma unroll
        for (int r = 0; r < 4; ++r) {
            int prow = m0 + mi * 16 + gk * 4 + r;
            conv_out[((b * HWN) + prow) * NCH + ch] = acc[mi][r] * INV_SCALE_QK + bias;
        }
}

// ---------------------------------------------------------------------------
// K2b: per-pixel LN -> GELU -> offset proj -> pos/ref + per-key precompute.
// ---------------------------------------------------------------------------
__global__ __launch_bounds__(384) void ln_offset_kernel(
    const float* __restrict__ co, const float* __restrict__ ln_g,
    const float* __restrict__ ln_b, const float* __restrict__ w_offp,
    float* __restrict__ pos_out, float* __restrict__ ref_out,
    float4* __restrict__ kw4, int* __restrict__ kbase)
{
    const int pg = blockIdx.x;
    const int b = pg >> 10, p = pg & 1023;
    const int i = p >> 5, j = p & 31;
    const int tid = threadIdx.x;
    const int g = tid >> 6, lane = tid & 63;

    __shared__ float red[6][2];

    float v = co[pg * NCH + tid];
    float s1 = v, s2 = v * v;
#pragma unroll
    for (int off = 32; off > 0; off >>= 1) {
        s1 += __shfl_xor(s1, off);
        s2 += __shfl_xor(s2, off);
    }
    if (lane == 0) { red[g][0] = s1; red[g][1] = s2; }
    __syncthreads();
    float t1s = 0.f, t2s = 0.f;
#pragma unroll
    for (int w = 0; w < 6; ++w) { t1s += red[w][0]; t2s += red[w][1]; }
    float mu  = t1s * (1.f / 384.f);
    float var = t2s * (1.f / 384.f) - mu * mu;
    float rs2 = rsqrtf(var + 1e-3f);
    float on = (v - mu) * rs2 * ln_g[tid] + ln_b[tid];
    float t = 0.7978845608028654f * (on + 0.044715f * on * on * on);
    float ge = on * 0.5f * (1.f + tanhf(t));

    float t0 = ge * w_offp[lane * 2 + 0];
    float t1 = ge * w_offp[lane * 2 + 1];
#pragma unroll
    for (int off = 32; off > 0; off >>= 1) {
        t0 += __shfl_xor(t0, off);
        t1 += __shfl_xor(t1, off);
    }
    if (lane == 0) {
        float o0 = tanhf(t0) * 16.f + (float)j;   // pos.x
        float o1 = tanhf(t1) * 16.f + (float)i;   // pos.y
        int kidx = (b * NGG + g) * HWN + p;
        pos_out[kidx * 2]     = o0; pos_out[kidx * 2 + 1] = o1;
        ref_out[kidx * 2]     = (float)j; ref_out[kidx * 2 + 1] = (float)i;
        float mp1 = -o1, mp0 = -o0;
        float fx = floorf(mp1), fy = floorf(mp0);
        float wx = mp1 - fx, wy = mp0 - fy;
        float4 w4;
        w4.x = (1.f - wx) * (1.f - wy);
        w4.y = wx * (1.f - wy);
        w4.z = (1.f - wx) * wy;
        w4.w = wx * wy;
        kw4[kidx] = w4;
        kbase[kidx] = ((int)fx & 0xFFFF) | ((int)fy << 16);
    }
}

// ---------------------------------------------------------------------------
// K3: MFMA flash attention, 4-way key-split (exact R4-proven version).
// Block = 4 waves x same 16 queries; wave w owns keys [256w, 256w+256).
// kw4/kbase/RPE staged in LDS; fp32 obuf combine. Grid (64,24).
// ---------------------------------------------------------------------------
__global__ __launch_bounds__(256) void attn_mfma(
    const unsigned short* __restrict__ Qg, const unsigned short* __restrict__ Kb,
    const unsigned short* __restrict__ Vt, const float4* __restrict__ kw4,
    const int* __restrict__ kbase, const float* __restrict__ rpad,
    unsigned short* __restrict__ o_bf)
{
    const int bh = blockIdx.y;
    const int b = bh / NHH;
    const int h = bh - b * NHH;
    const int tid = threadIdx.x;
    const int wid = tid >> 6;
    const int lane = tid & 63;
    const int g = lane >> 4;
    const int l15 = lane & 15;
    const int q = blockIdx.x * 16 + l15;

    __shared__ float rsT[67 * 68];
    __shared__ float4 kw4s[HWN];
    __shared__ int kbs[HWN];
    __shared__ unsigned short P_lds[4][16][40];
    __shared__ float obuf[4][16][34];
    __shared__ float mlbuf[4][2][16];

    {
        const float4* rp = (const float4*)(rpad + h * (67 * 68));
        float4* rd = (float4*)rsT;
        for (int idx = tid; idx < (67 * 68) / 4; idx += 256) rd[idx] = rp[idx];
        const float4* kwg = kw4 + (b * NGG + (h >> 1)) * HWN;
        for (int idx = tid; idx < HWN; idx += 256) kw4s[idx] = kwg[idx];
        const int* kbg2 = kbase + (b * NGG + (h >> 1)) * HWN;
        for (int idx = tid; idx < HWN; idx += 256) kbs[idx] = kbg2[idx];
    }

    short8 qf = *(const short8*)(Qg + ((b * NGG + (h >> 1)) * HWN + q) * 64 + (h & 1) * 32 + g * 8);
    const int qi = q >> 5;
    const int qj = q & 31;

    const unsigned short* kbg = Kb + (bh * HWN) * DHH;
    const unsigned short* vbase = Vt + (bh * DHH) * HWN;

    f32x4 oacc[2] = {};
    float m = -1e30f, lp = 0.f;
    const f32x4 z4 = {0.f, 0.f, 0.f, 0.f};

    __syncthreads();

#pragma unroll 1
    for (int c = 0; c < 8; ++c) {
        const int kc0 = wid * 256 + c * 32;
        f32x4 st[2];
#pragma unroll
        for (int t = 0; t < 2; ++t) {
            short8 kf = *(const short8*)(kbg + (kc0 + t * 16 + l15) * DHH + g * 8);
            st[t] = __builtin_amdgcn_mfma_f32_16x16x32_bf16(kf, qf, z4, 0, 0, 0);
        }
#pragma unroll
        for (int t = 0; t < 2; ++t) {
#pragma unroll
            for (int r = 0; r < 4; ++r) {
                int k = kc0 + t * 16 + g * 4 + r;
                float4 w4 = kw4s[k];
                int bp = kbs[k];
                int ix = qi + ((bp << 16) >> 16);
                int iy = qj + (bp >> 16);
                int cx = min(max(ix, -2), 63) + 2;
                int cy = min(max(iy, -2), 63) + 2;
                int a = cy * 68 + cx;
                st[t][r] += w4.x * rsT[a] + w4.y * rsT[a + 1]
                          + w4.z * rsT[a + 68] + w4.w * rsT[a + 69];
            }
        }
        float cm = fmaxf(fmaxf(fmaxf(st[0][0], st[0][1]), fmaxf(st[0][2], st[0][3])),
                         fmaxf(fmaxf(st[1][0], st[1][1]), fmaxf(st[1][2], st[1][3])));
        cm = fmaxf(cm, __shfl_xor(cm, 16));
        cm = fmaxf(cm, __shfl_xor(cm, 32));
        if (cm > m + 8.f) {
            float scl = __expf(m - cm);
            m = cm;
            lp *= scl;
            oacc[0] *= scl;
            oacc[1] *= scl;
        }
#pragma unroll
        for (int t = 0; t < 2; ++t) {
            float p0 = __expf(st[t][0] - m);
            float p1 = __expf(st[t][1] - m);
            float p2 = __expf(st[t][2] - m);
            float p3 = __expf(st[t][3] - m);
            lp += (p0 + p1) + (p2 + p3);
            uint2 pk;
            pk.x = (unsigned)f2bf(p0) | ((unsigned)f2bf(p1) << 16);
            pk.y = (unsigned)f2bf(p2) | ((unsigned)f2bf(p3) << 16);
            *(uint2*)&P_lds[wid][l15][t * 16 + g * 4] = pk;
        }
        short8 pf = *(const short8*)&P_lds[wid][l15][g * 8];
#pragma unroll
        for (int dt = 0; dt < 2; ++dt) {
            short8 vf = *(const short8*)(vbase + (dt * 16 + l15) * HWN + kc0 + g * 8);
            oacc[dt] = __builtin_amdgcn_mfma_f32_16x16x32_bf16(vf, pf, oacc[dt], 0, 0, 0);
        }
    }

    lp += __shfl_xor(lp, 16);
    lp += __shfl_xor(lp, 32);
    if (g == 0) {
        mlbuf[wid][0][l15] = m;
        mlbuf[wid][1][l15] = lp;
    }
#pragma unroll
    for (int dt = 0; dt < 2; ++dt)
#pragma unroll
        for (int r = 0; r < 4; ++r)
            obuf[wid][l15][dt * 16 + g * 4 + r] = oacc[dt][r];
    __syncthreads();

    const int q16 = tid >> 4;
    const int dp = (tid & 15) * 2;
    float m0 = mlbuf[0][0][q16], m1 = mlbuf[1][0][q16];
    float m2 = mlbuf[2][0][q16], m3 = mlbuf[3][0][q16];
    float mstar = fmaxf(fmaxf(m0, m1), fmaxf(m2, m3));
    float w0 = __expf(m0 - mstar), w1 = __expf(m1 - mstar);
    float w2 = __expf(m2 - mstar), w3 = __expf(m3 - mstar);
    float lsum = w0 * mlbuf[0][1][q16] + w1 * mlbuf[1][1][q16]
               + w2 * mlbuf[2][1][q16] + w3 * mlbuf[3][1][q16];
    float inv = 1.f / lsum;
    unsigned out2 = 0;
#pragma unroll
    for (int u = 0; u < 2; ++u) {
        int d = dp + u;
        float o = w0 * obuf[0][q16][d] + w1 * obuf[1][q16][d]
                + w2 * obuf[2][q16][d] + w3 * obuf[3][q16][d];
        unsigned short s = f2bf(o * inv);
        out2 |= ((unsigned)s) << (u * 16);
    }
    int qn2 = blockIdx.x * 16 + q16;
    *(unsigned*)&o_bf[((b * HWN) + qn2) * NCH + h * DHH + dp] = out2;
}

// ---------------------------------------------------------------------------
extern "C" void kernel_launch(void* const* d_in, const int* in_sizes, int n_in,
                              void* d_out, int out_size, void* d_ws, size_t ws_size,
                              hipStream_t stream) {
    (void)in_sizes; (void)n_in; (void)out_size; (void)ws_size;
    const float* x      = (const float*)d_in[0];
    const float* w_off  = (const float*)d_in[1];
    const float* b_off  = (const float*)d_in[2];
    const float* ln_g   = (const float*)d_in[3];
    const float* ln_b   = (const float*)d_in[4];
    const float* w_offp = (const float*)d_in[5];
    const float* wq     = (const float*)d_in[6];
    const float* bq     = (const float*)d_in[7];
    const float* wk     = (const float*)d_in[8];
    const float* bk     = (const float*)d_in[9];
    const float* wv     = (const float*)d_in[10];
    const float* bv     = (const float*)d_in[11];
    const float* wo     = (const float*)d_in[12];
    const float* bo     = (const float*)d_in[13];
    const float* rpe    = (const float*)d_in[14];

    float* out     = (float*)d_out;
    float* y_out   = out;             // 786432
    float* pos_out = out + 786432;    // 24576
    float* ref_out = out + 811008;    // 24576

    float* ws = (float*)d_ws;
    unsigned short* Qg   = (unsigned short*)(ws);            // 786432 bf16
    unsigned short* Kb   = (unsigned short*)(ws + 393216);   // 786432 bf16
    unsigned short* Vt   = (unsigned short*)(ws + 786432);   // 786432 bf16
    unsigned short* o_bf = (unsigned short*)(ws + 1179648);  // 786432 bf16
    float*  rpad  = ws + 1376256;                            // 54672 f32
    float4* kw4   = (float4*)(ws + 1430928);                 // 12288 float4
    int*    kbase = (int*)(ws + 1480080);                    // 12288 int
    unsigned short* Wg = (unsigned short*)(ws + 1492368);    // 221184 bf16
    float* conv_ws = ws + 1602960;                           // 786432 f32
    unsigned short* Wt = (unsigned short*)(ws + 2389392);    // 589824 bf16
    unsigned short* xb = (unsigned short*)(ws + 2684304);    // 786432 bf16

    // K0: padded RPE + transposed bf16 conv/proj weights + bf16 x
    prep_kernel<<<dim3((PREP_TOT + 255) / 256), 256, 0, stream>>>(
        rpe, w_off, wq, wk, wv, wo, x, rpad, Wg, Wt, xb);

    // K1: q/k/v projections -> Qg (group-major, scaled), Kb, Vt
    gemm_mfma<<<dim3(32, 6, 3), 256, 0, stream>>>(
        xb, Wt, bq, bk, bv, nullptr, Qg, Kb, Vt, 1);

    // K2a: grouped conv via shifted-window MFMA (4 waves/block)
    conv_mfma<<<dim3(32, 12), 256, 0, stream>>>(Qg, Wg, b_off, conv_ws);

    // K2b: LN + GELU + offset proj -> pos/ref + per-key precompute
    ln_offset_kernel<<<dim3(2048), 384, 0, stream>>>(
        conv_ws, ln_g, ln_b, w_offp, pos_out, ref_out, kw4, kbase);

    // K3: MFMA flash attention (R4-proven, LDS-staged bias tables)
    attn_mfma<<<dim3(64, 24), 256, 0, stream>>>(
        Qg, Kb, Vt, kw4, kbase, rpad, o_bf);

    // K4: output projection -> y
    gemm_mfma<<<dim3(32, 6, 1), 256, 0, stream>>>(
        o_bf, Wt + 3 * NCH * NCH, bo, bo, bo, y_out, nullptr, nullptr, nullptr, 0);
}

// Round 9
// 87.223 us; speedup vs baseline: 1.1154x; 1.0608x over previous
//
#include <hip/hip_runtime.h>
#include <cmath>

#define HH 32
#define WW 32
#define HWN 1024
#define NCH 384
#define NHH 12
#define DHH 32
#define NGG 6

typedef __attribute__((ext_vector_type(8))) short short8;
typedef __attribute__((ext_vector_type(4))) float f32x4;

static constexpr float SCALE_QK = 0.17677669529663689f;     // 32^-0.5
static constexpr float INV_SCALE_QK = 5.656854249492381f;   // 32^0.5

__device__ inline unsigned short f2bf(float f) {
    union { float f; unsigned u; } v; v.f = f;
    return (unsigned short)((v.u + 0x7FFFu + ((v.u >> 16) & 1u)) >> 16);  // RNE
}
__device__ inline float bf2f(unsigned short s) {
    union { unsigned u; float f; } v; v.u = ((unsigned)s) << 16;
    return v.f;
}
__device__ inline float ubf_lo(unsigned u) {
    union { unsigned x; float f; } v; v.x = u << 16; return v.f;
}
__device__ inline float ubf_hi(unsigned u) {
    union { unsigned x; float f; } v; v.x = u & 0xFFFF0000u; return v.f;
}

// ---------------------------------------------------------------------------
// K0 prep: (a) bf16 head-pair-packed zero-padded RPE planes
//              rpad2b[6][4490] uint: cell a2 = row*67+col (coords +2),
//              lo16 = head g*2, hi16 = head g*2+1;
//          (b) bf16 transposed conv weights Wg[n=384][k=576];
//          (c) bf16 transposed proj weights Wt[4][384][384] (q,k,v,o);
//          (d) bf16 copy of x.
// ---------------------------------------------------------------------------
#define RP2B_PLANE 4490                // 67*67 = 4489, +1 pad
#define RP2B_N (6 * RP2B_PLANE)
#define WG_N   (384 * 576)
#define WT_N   (4 * 384 * 384)
#define XB_N   (2048 * 384)
#define OFF1 RP2B_N
#define OFF2 (OFF1 + WG_N)
#define OFF3 (OFF2 + WT_N)
#define PREP_TOT (OFF3 + XB_N)
__global__ __launch_bounds__(256) void prep_kernel(
    const float* __restrict__ rpe, const float* __restrict__ w_off,
    const float* __restrict__ wq, const float* __restrict__ wk,
    const float* __restrict__ wv, const float* __restrict__ wo,
    const float* __restrict__ x,
    unsigned* __restrict__ rpad2b, unsigned short* __restrict__ Wg,
    unsigned short* __restrict__ Wt, unsigned short* __restrict__ xb)
{
    int idx = blockIdx.x * 256 + threadIdx.x;
    if (idx < OFF1) {
        int gp = idx / RP2B_PLANE;
        int a2 = idx - gp * RP2B_PLANE;
        int row = a2 / 67, col = a2 - row * 67;
        int r = row - 2, c = col - 2;
        unsigned pk = 0;
        if (a2 < 4489 && r >= 0 && r < 63 && c >= 0 && c < 63) {
            unsigned short lo = f2bf(rpe[(r * 63 + c) * NHH + gp * 2]);
            unsigned short hi = f2bf(rpe[(r * 63 + c) * NHH + gp * 2 + 1]);
            pk = (unsigned)lo | ((unsigned)hi << 16);
        }
        rpad2b[idx] = pk;
    } else if (idx < OFF2) {
        int w = idx - OFF1;
        int n = w / 576, k = w - n * 576;
        Wg[n * 576 + k] = f2bf(w_off[k * NCH + n]);
    } else if (idx < OFF3) {
        int w = idx - OFF2;
        int z = w / (NCH * NCH);
        int rem = w - z * (NCH * NCH);
        int n = rem / NCH, k = rem - n * NCH;
        const float* Wz = (z == 0) ? wq : (z == 1) ? wk : (z == 2) ? wv : wo;
        Wt[w] = f2bf(Wz[k * NCH + n]);
    } else if (idx < PREP_TOT) {
        int e = idx - OFF3;
        xb[e] = f2bf(x[e]);
    }
}

// ---------------------------------------------------------------------------
// MFMA GEMM, pure bf16 operands (A[m][k], Wt[n][k]), fp32 accum. (proven R5/R7)
// ---------------------------------------------------------------------------
__global__ __launch_bounds__(256) void gemm_mfma(
    const unsigned short* __restrict__ Abf, const unsigned short* __restrict__ Wt,
    const float* __restrict__ b0, const float* __restrict__ b1, const float* __restrict__ b2,
    float* __restrict__ Cf,
    unsigned short* __restrict__ Qg, unsigned short* __restrict__ Kb,
    unsigned short* __restrict__ Vt, int kmode)
{
    const int z = blockIdx.z;
    const unsigned short* Wm = Wt + z * (NCH * NCH);
    const float* bm = (z == 0) ? b0 : (z == 1) ? b1 : b2;
    const int lane = threadIdx.x & 63;
    const int wid  = threadIdx.x >> 6;
    const int g    = lane >> 4;
    const int l15  = lane & 15;
    const int m0w  = blockIdx.x * 64 + (wid >> 1) * 32;
    const int n0w  = blockIdx.y * 64 + (wid & 1) * 32;

    f32x4 acc[2][2] = {};

#pragma unroll 4
    for (int k0 = 0; k0 < NCH; k0 += 32) {
        short8 af[2], bfr[2];
#pragma unroll
        for (int i = 0; i < 2; ++i)
            af[i] = *(const short8*)(Abf + (m0w + i * 16 + l15) * NCH + k0 + g * 8);
#pragma unroll
        for (int j = 0; j < 2; ++j)
            bfr[j] = *(const short8*)(Wm + (n0w + j * 16 + l15) * NCH + k0 + g * 8);
#pragma unroll
        for (int i = 0; i < 2; ++i)
#pragma unroll
            for (int j = 0; j < 2; ++j)
                acc[i][j] = __builtin_amdgcn_mfma_f32_16x16x32_bf16(
                    af[i], bfr[j], acc[i][j], 0, 0, 0);
    }

    if (kmode == 0) {
#pragma unroll
        for (int i = 0; i < 2; ++i)
#pragma unroll
            for (int j = 0; j < 2; ++j) {
                int col = n0w + j * 16 + l15;
                float bias = bm[col];
#pragma unroll
                for (int r = 0; r < 4; ++r) {
                    int row = m0w + i * 16 + g * 4 + r;
                    Cf[row * NCH + col] = acc[i][j][r] + bias;
                }
            }
    } else if (z == 2) {
#pragma unroll
        for (int i = 0; i < 2; ++i) {
            int krow = m0w + i * 16 + g * 4;
            int b_ = krow >> 10, kk = krow & 1023;
#pragma unroll
            for (int j = 0; j < 2; ++j) {
                int col = n0w + j * 16 + l15;
                int h = col >> 5, d = col & 31;
                float bias = bm[col];
                unsigned short s0 = f2bf(acc[i][j][0] + bias);
                unsigned short s1 = f2bf(acc[i][j][1] + bias);
                unsigned short s2 = f2bf(acc[i][j][2] + bias);
                unsigned short s3 = f2bf(acc[i][j][3] + bias);
                uint2 pk;
                pk.x = (unsigned)s0 | ((unsigned)s1 << 16);
                pk.y = (unsigned)s2 | ((unsigned)s3 << 16);
                *(uint2*)&Vt[(((b_ * NHH) + h) * DHH + d) * HWN + kk] = pk;
            }
        }
    } else if (z == 0) {
        // Qg group-major: [b][g6][p][c64], c = (h&1)*32 + d, scaled
#pragma unroll
        for (int i = 0; i < 2; ++i)
#pragma unroll
            for (int j = 0; j < 2; ++j) {
                int col = n0w + j * 16 + l15;
                int h = col >> 5, d = col & 31;
                float bias = bm[col];
#pragma unroll
                for (int r = 0; r < 4; ++r) {
                    int row = m0w + i * 16 + g * 4 + r;
                    int b_ = row >> 10, q = row & 1023;
                    Qg[(((b_ * NGG + (h >> 1)) * HWN + q) * 64) + (h & 1) * 32 + d] =
                        f2bf((acc[i][j][r] + bias) * SCALE_QK);
                }
            }
    } else {
#pragma unroll
        for (int i = 0; i < 2; ++i)
#pragma unroll
            for (int j = 0; j < 2; ++j) {
                int col = n0w + j * 16 + l15;
                int h = col >> 5, d = col & 31;
                float bias = bm[col];
#pragma unroll
                for (int r = 0; r < 4; ++r) {
                    int row = m0w + i * 16 + g * 4 + r;
                    int b_ = row >> 10, q = row & 1023;
                    Kb[(((b_ * NHH) + h) * HWN + q) * DHH + d] = f2bf(acc[i][j][r] + bias);
                }
            }
    }
}

// ---------------------------------------------------------------------------
// K2a: grouped 3x3 conv as shifted-window MFMA GEMM (proven R5/R7).
// ---------------------------------------------------------------------------
__global__ __launch_bounds__(256) void conv_mfma(
    const unsigned short* __restrict__ Qg, const unsigned short* __restrict__ Wg,
    const float* __restrict__ b_off, float* __restrict__ conv_out)
{
    const int bg = blockIdx.y;
    const int b = bg / NGG, g = bg - b * NGG;
    const int m0 = blockIdx.x * 32;
    const int tid = threadIdx.x;
    const int wid = tid >> 6;
    const int lane = tid & 63;
    const int l15 = lane & 15, gk = lane >> 4;

    const unsigned short* Ab = Qg + (bg * HWN) * 64;
    const unsigned short* Bb = Wg + (g * 64 + wid * 16) * 576;

    f32x4 acc[2] = {};
    const int pr0 = m0 + l15, pr1 = m0 + 16 + l15;
    const int irow = m0 >> 5;
    const int4 zz = {0, 0, 0, 0};

#pragma unroll
    for (int kh = 0; kh < 3; ++kh) {
        int ii = irow + kh - 1;
        if ((unsigned)ii >= (unsigned)HH) continue;
#pragma unroll
        for (int kw = 0; kw < 3; ++kw) {
            int dp = (kh - 1) * 32 + (kw - 1);
            bool v0 = (unsigned)(l15 + kw - 1) < (unsigned)WW;
            bool v1 = (unsigned)(16 + l15 + kw - 1) < (unsigned)WW;
            int p0 = min(max(pr0 + dp, 0), HWN - 1);
            int p1 = min(max(pr1 + dp, 0), HWN - 1);
            const int kt = (kh * 3 + kw) * 64;
#pragma unroll
            for (int cc = 0; cc < 2; ++cc) {
                int4 ra = *(const int4*)(Ab + p0 * 64 + cc * 32 + gk * 8);
                int4 rb = *(const int4*)(Ab + p1 * 64 + cc * 32 + gk * 8);
                int4 a0i = v0 ? ra : zz;
                int4 a1i = v1 ? rb : zz;
                short8 a0 = *(short8*)&a0i;
                short8 a1 = *(short8*)&a1i;
                short8 bf = *(const short8*)(Bb + l15 * 576 + kt + cc * 32 + gk * 8);
                acc[0] = __builtin_amdgcn_mfma_f32_16x16x32_bf16(a0, bf, acc[0], 0, 0, 0);
                acc[1] = __builtin_amdgcn_mfma_f32_16x16x32_bf16(a1, bf, acc[1], 0, 0, 0);
            }
        }
    }

    const int ch = g * 64 + wid * 16 + l15;
    const float bias = b_off[ch];
#pragma unroll
    for (int mi = 0; mi < 2; ++mi)
#pragma unroll
        for (int r = 0; r < 4; ++r) {
            int prow = m0 + mi * 16 + gk * 4 + r;
            conv_out[((b * HWN) + prow) * NCH + ch] = acc[mi][r] * INV_SCALE_QK + bias;
        }
}

// ---------------------------------------------------------------------------
// K2b: per-pixel LN -> GELU -> offset proj -> pos/ref + per-key precompute.
// ---------------------------------------------------------------------------
__global__ __launch_bounds__(384) void ln_offset_kernel(
    const float* __restrict__ co, const float* __restrict__ ln_g,
    const float* __restrict__ ln_b, const float* __restrict__ w_offp,
    float* __restrict__ pos_out, float* __restrict__ ref_out,
    float4* __restrict__ kw4, int* __restrict__ kbase)
{
    const int pg = blockIdx.x;
    const int b = pg >> 10, p = pg & 1023;
    const int i = p >> 5, j = p & 31;
    const int tid = threadIdx.x;
    const int g = tid >> 6, lane = tid & 63;

    __shared__ float red[6][2];

    float v = co[pg * NCH + tid];
    float s1 = v, s2 = v * v;
#pragma unroll
    for (int off = 32; off > 0; off >>= 1) {
        s1 += __shfl_xor(s1, off);
        s2 += __shfl_xor(s2, off);
    }
    if (lane == 0) { red[g][0] = s1; red[g][1] = s2; }
    __syncthreads();
    float t1s = 0.f, t2s = 0.f;
#pragma unroll
    for (int w = 0; w < 6; ++w) { t1s += red[w][0]; t2s += red[w][1]; }
    float mu  = t1s * (1.f / 384.f);
    float var = t2s * (1.f / 384.f) - mu * mu;
    float rs2 = rsqrtf(var + 1e-3f);
    float on = (v - mu) * rs2 * ln_g[tid] + ln_b[tid];
    float t = 0.7978845608028654f * (on + 0.044715f * on * on * on);
    float ge = on * 0.5f * (1.f + tanhf(t));

    float t0 = ge * w_offp[lane * 2 + 0];
    float t1 = ge * w_offp[lane * 2 + 1];
#pragma unroll
    for (int off = 32; off > 0; off >>= 1) {
        t0 += __shfl_xor(t0, off);
        t1 += __shfl_xor(t1, off);
    }
    if (lane == 0) {
        float o0 = tanhf(t0) * 16.f + (float)j;   // pos.x
        float o1 = tanhf(t1) * 16.f + (float)i;   // pos.y
        int kidx = (b * NGG + g) * HWN + p;
        pos_out[kidx * 2]     = o0; pos_out[kidx * 2 + 1] = o1;
        ref_out[kidx * 2]     = (float)j; ref_out[kidx * 2 + 1] = (float)i;
        float mp1 = -o1, mp0 = -o0;
        float fx = floorf(mp1), fy = floorf(mp0);
        float wx = mp1 - fx, wy = mp0 - fy;
        float4 w4;
        w4.x = (1.f - wx) * (1.f - wy);
        w4.y = wx * (1.f - wy);
        w4.z = (1.f - wx) * wy;
        w4.w = wx * wy;
        kw4[kidx] = w4;
        kbase[kidx] = ((int)fx & 0xFFFF) | ((int)fy << 16);
    }
}

// ---------------------------------------------------------------------------
// K3: MFMA flash attention, head-PAIRED (both heads of a group per block).
// Block = (b,g): 4 waves x 16 queries, wave = 256-key chunk, 2 heads each.
// RPE staged as bf16 head-pairs (1 uint/cell): one gather serves both heads
// with the same LDS-read count as the proven single-head kernel.
// kw4/kbase staged ONCE per group (was twice). Grid (64,12) = 768 = 3/CU,
// exactly one scheduling pass. Combine: per-wave-normalized bf16 partials
// + logsumexp weights s = m + ln(l) (exact algebra).
// LDS = 17.96+16.38+4.10+5.12+9.22+0.51 = 53.3 KB -> 3 blocks/CU.
// ---------------------------------------------------------------------------
__global__ __launch_bounds__(256) void attn_mfma(
    const unsigned short* __restrict__ Qg, const unsigned short* __restrict__ Kb,
    const unsigned short* __restrict__ Vt, const float4* __restrict__ kw4,
    const int* __restrict__ kbase, const unsigned* __restrict__ rpad2b,
    unsigned short* __restrict__ o_bf)
{
    const int bg = blockIdx.y;            // 0..11 = b*6+g
    const int b = bg / NGG, g = bg - b * NGG;
    const int tid = threadIdx.x;
    const int wid = tid >> 6;             // key chunk 0..3
    const int lane = tid & 63;
    const int ks = lane >> 4;             // k-slot 0..3
    const int l15 = lane & 15;            // query within tile
    const int q = blockIdx.x * 16 + l15;

    __shared__ unsigned rs2[RP2B_PLANE];              // 17,960 B
    __shared__ float4 kw4s[HWN];                      // 16,384 B
    __shared__ int kbs[HWN];                          //  4,096 B
    __shared__ unsigned short P_lds[4][16][40];       //  5,120 B (reused per head)
    __shared__ unsigned short obuf[2][4][16][36];     //  9,216 B
    __shared__ float sw_s[2][4][16];                  //    512 B

    {
        const unsigned* rp = rpad2b + g * RP2B_PLANE;   // <-- group-indexed (R6 bug fixed)
        for (int idx = tid; idx < RP2B_PLANE; idx += 256) rs2[idx] = rp[idx];
        const float4* kwg = kw4 + bg * HWN;
        for (int idx = tid; idx < HWN; idx += 256) kw4s[idx] = kwg[idx];
        const int* kbg2 = kbase + bg * HWN;
        for (int idx = tid; idx < HWN; idx += 256) kbs[idx] = kbg2[idx];
    }

    short8 qf[2];
#pragma unroll
    for (int e = 0; e < 2; ++e)
        qf[e] = *(const short8*)(Qg + ((bg * HWN) + q) * 64 + e * 32 + ks * 8);
    const int qi = q >> 5;
    const int qj = q & 31;

    const unsigned short* kb0 = Kb + ((b * NHH + g * 2) * HWN) * DHH;
    const unsigned short* vb0 = Vt + ((b * NHH + g * 2) * DHH) * HWN;

    f32x4 oacc[2][2] = {};
    float m[2] = {-1e30f, -1e30f};
    float lp[2] = {0.f, 0.f};
    const f32x4 z4 = {0.f, 0.f, 0.f, 0.f};

    __syncthreads();

#pragma unroll 1
    for (int c = 0; c < 8; ++c) {
        const int kc0 = wid * 256 + c * 32;
        f32x4 st[2][2];
#pragma unroll
        for (int e = 0; e < 2; ++e)
#pragma unroll
            for (int t = 0; t < 2; ++t) {
                short8 kf = *(const short8*)(kb0 + e * (HWN * DHH) + (kc0 + t * 16 + l15) * DHH + ks * 8);
                st[e][t] = __builtin_amdgcn_mfma_f32_16x16x32_bf16(kf, qf[e], z4, 0, 0, 0);
            }
        // shared bilinear gather: one uint per corner = both heads (bf16 pair)
#pragma unroll
        for (int t = 0; t < 2; ++t) {
#pragma unroll
            for (int r = 0; r < 4; ++r) {
                int k = kc0 + t * 16 + ks * 4 + r;
                float4 w4 = kw4s[k];
                int bp = kbs[k];
                int ix = qi + ((bp << 16) >> 16);
                int iy = qj + (bp >> 16);
                int cx = min(max(ix, -2), 63) + 2;
                int cy = min(max(iy, -2), 63) + 2;
                int a = cy * 67 + cx;
                unsigned u00 = rs2[a],      u01 = rs2[a + 1];
                unsigned u10 = rs2[a + 67], u11 = rs2[a + 68];
                st[0][t][r] += w4.x * ubf_lo(u00) + w4.y * ubf_lo(u01)
                             + w4.z * ubf_lo(u10) + w4.w * ubf_lo(u11);
                st[1][t][r] += w4.x * ubf_hi(u00) + w4.y * ubf_hi(u01)
                             + w4.z * ubf_hi(u10) + w4.w * ubf_hi(u11);
            }
        }
#pragma unroll
        for (int e = 0; e < 2; ++e) {
            float cm = fmaxf(fmaxf(fmaxf(st[e][0][0], st[e][0][1]), fmaxf(st[e][0][2], st[e][0][3])),
                             fmaxf(fmaxf(st[e][1][0], st[e][1][1]), fmaxf(st[e][1][2], st[e][1][3])));
            cm = fmaxf(cm, __shfl_xor(cm, 16));
            cm = fmaxf(cm, __shfl_xor(cm, 32));
            if (cm > m[e] + 8.f) {
                float scl = __expf(m[e] - cm);
                m[e] = cm;
                lp[e] *= scl;
                oacc[e][0] *= scl;
                oacc[e][1] *= scl;
            }
#pragma unroll
            for (int t = 0; t < 2; ++t) {
                float p0 = __expf(st[e][t][0] - m[e]);
                float p1 = __expf(st[e][t][1] - m[e]);
                float p2 = __expf(st[e][t][2] - m[e]);
                float p3 = __expf(st[e][t][3] - m[e]);
                lp[e] += (p0 + p1) + (p2 + p3);
                uint2 pk;
                pk.x = (unsigned)f2bf(p0) | ((unsigned)f2bf(p1) << 16);
                pk.y = (unsigned)f2bf(p2) | ((unsigned)f2bf(p3) << 16);
                *(uint2*)&P_lds[wid][l15][t * 16 + ks * 4] = pk;
            }
            short8 pf = *(const short8*)&P_lds[wid][l15][ks * 8];
#pragma unroll
            for (int dt = 0; dt < 2; ++dt) {
                short8 vf = *(const short8*)(vb0 + e * (DHH * HWN) + (dt * 16 + l15) * HWN + kc0 + ks * 8);
                oacc[e][dt] = __builtin_amdgcn_mfma_f32_16x16x32_bf16(vf, pf, oacc[e][dt], 0, 0, 0);
            }
        }
    }

    // per-wave normalize; deposit bf16 partials + s = m + ln(l)
#pragma unroll
    for (int e = 0; e < 2; ++e) {
        float l = lp[e];
        l += __shfl_xor(l, 16);
        l += __shfl_xor(l, 32);
        float inv = 1.f / l;
#pragma unroll
        for (int dt = 0; dt < 2; ++dt) {
            unsigned short a0 = f2bf(oacc[e][dt][0] * inv);
            unsigned short a1 = f2bf(oacc[e][dt][1] * inv);
            unsigned short a2 = f2bf(oacc[e][dt][2] * inv);
            unsigned short a3 = f2bf(oacc[e][dt][3] * inv);
            uint2 pk;
            pk.x = (unsigned)a0 | ((unsigned)a1 << 16);
            pk.y = (unsigned)a2 | ((unsigned)a3 << 16);
            *(uint2*)&obuf[e][wid][l15][dt * 16 + ks * 4] = pk;
        }
        if (ks == 0) sw_s[e][wid][l15] = m[e] + __logf(l);
    }
    __syncthreads();

    // combine 4 key-chunk partials: thread = (e2, q16, d-quad)
    const int e2 = tid >> 7;
    const int q16 = (tid >> 3) & 15;
    const int dg = tid & 7;
    float s0 = sw_s[e2][0][q16], s1 = sw_s[e2][1][q16];
    float s2 = sw_s[e2][2][q16], s3 = sw_s[e2][3][q16];
    float smax = fmaxf(fmaxf(s0, s1), fmaxf(s2, s3));
    float u0 = __expf(s0 - smax), u1 = __expf(s1 - smax);
    float u2 = __expf(s2 - smax), u3 = __expf(s3 - smax);
    float inv = 1.f / (u0 + u1 + u2 + u3);
    float uw[4] = {u0, u1, u2, u3};
    float o[4] = {0.f, 0.f, 0.f, 0.f};
#pragma unroll
    for (int w = 0; w < 4; ++w) {
        uint2 pk = *(const uint2*)&obuf[e2][w][q16][dg * 4];
        o[0] += uw[w] * bf2f((unsigned short)(pk.x & 0xFFFF));
        o[1] += uw[w] * bf2f((unsigned short)(pk.x >> 16));
        o[2] += uw[w] * bf2f((unsigned short)(pk.y & 0xFFFF));
        o[3] += uw[w] * bf2f((unsigned short)(pk.y >> 16));
    }
    uint2 res;
    res.x = (unsigned)f2bf(o[0] * inv) | ((unsigned)f2bf(o[1] * inv) << 16);
    res.y = (unsigned)f2bf(o[2] * inv) | ((unsigned)f2bf(o[3] * inv) << 16);
    int qn = blockIdx.x * 16 + q16;
    int col = (g * 2 + e2) * DHH + dg * 4;
    *(uint2*)&o_bf[((b * HWN) + qn) * NCH + col] = res;
}

// ---------------------------------------------------------------------------
extern "C" void kernel_launch(void* const* d_in, const int* in_sizes, int n_in,
                              void* d_out, int out_size, void* d_ws, size_t ws_size,
                              hipStream_t stream) {
    (void)in_sizes; (void)n_in; (void)out_size; (void)ws_size;
    const float* x      = (const float*)d_in[0];
    const float* w_off  = (const float*)d_in[1];
    const float* b_off  = (const float*)d_in[2];
    const float* ln_g   = (const float*)d_in[3];
    const float* ln_b   = (const float*)d_in[4];
    const float* w_offp = (const float*)d_in[5];
    const float* wq     = (const float*)d_in[6];
    const float* bq     = (const float*)d_in[7];
    const float* wk     = (const float*)d_in[8];
    const float* bk     = (const float*)d_in[9];
    const float* wv     = (const float*)d_in[10];
    const float* bv     = (const float*)d_in[11];
    const float* wo     = (const float*)d_in[12];
    const float* bo     = (const float*)d_in[13];
    const float* rpe    = (const float*)d_in[14];

    float* out     = (float*)d_out;
    float* y_out   = out;             // 786432
    float* pos_out = out + 786432;    // 24576
    float* ref_out = out + 811008;    // 24576

    float* ws = (float*)d_ws;
    unsigned short* Qg   = (unsigned short*)(ws);            // 786432 bf16
    unsigned short* Kb   = (unsigned short*)(ws + 393216);   // 786432 bf16
    unsigned short* Vt   = (unsigned short*)(ws + 786432);   // 786432 bf16
    unsigned short* o_bf = (unsigned short*)(ws + 1179648);  // 786432 bf16
    unsigned* rpad2b = (unsigned*)(ws + 1376256);            // 26940 uint
    float4* kw4   = (float4*)(ws + 1430928);                 // 12288 float4
    int*    kbase = (int*)(ws + 1480080);                    // 12288 int
    unsigned short* Wg = (unsigned short*)(ws + 1492368);    // 221184 bf16
    float* conv_ws = ws + 1602960;                           // 786432 f32
    unsigned short* Wt = (unsigned short*)(ws + 2389392);    // 589824 bf16
    unsigned short* xb = (unsigned short*)(ws + 2684304);    // 786432 bf16

    // K0: bf16 head-pair RPE planes + transposed bf16 weights + bf16 x
    prep_kernel<<<dim3((PREP_TOT + 255) / 256), 256, 0, stream>>>(
        rpe, w_off, wq, wk, wv, wo, x, rpad2b, Wg, Wt, xb);

    // K1: q/k/v projections -> Qg (group-major, scaled), Kb, Vt
    gemm_mfma<<<dim3(32, 6, 3), 256, 0, stream>>>(
        xb, Wt, bq, bk, bv, nullptr, Qg, Kb, Vt, 1);

    // K2a: grouped conv via shifted-window MFMA (4 waves/block)
    conv_mfma<<<dim3(32, 12), 256, 0, stream>>>(Qg, Wg, b_off, conv_ws);

    // K2b: LN + GELU + offset proj -> pos/ref + per-key precompute
    ln_offset_kernel<<<dim3(2048), 384, 0, stream>>>(
        conv_ws, ln_g, ln_b, w_offp, pos_out, ref_out, kw4, kbase);

    // K3: head-paired MFMA flash attention (768 blocks = 3/CU, one pass)
    attn_mfma<<<dim3(64, 12), 256, 0, stream>>>(
        Qg, Kb, Vt, kw4, kbase, rpad2b, o_bf);

    // K4: output projection -> y
    gemm_mfma<<<dim3(32, 6, 1), 256, 0, stream>>>(
        o_bf, Wt + 3 * NCH * NCH, bo, bo, bo, y_out, nullptr, nullptr, nullptr, 0);
}